// Round 11
// baseline (463.778 us; speedup 1.0000x reference)
//
#include <hip/hip_runtime.h>
#include <hip/hip_bf16.h>

#define FDIM 128
#define BROWS 32     // i1 rows per bucket: bin = i1>>5, loc = i1&31
#define NBLK 128     // hist/scatter partitions: runs of ~8 = 32B per line per block

// ---- bf16 helpers (manual, RNE) ----
static __device__ __forceinline__ unsigned short f2bf(float x) {
    unsigned u = __float_as_uint(x);
    unsigned r = 0x7fffu + ((u >> 16) & 1u);
    return (unsigned short)((u + r) >> 16);
}
static __device__ __forceinline__ float bf_lo(unsigned u) { return __uint_as_float(u << 16); }
static __device__ __forceinline__ float bf_hi(unsigned u) { return __uint_as_float(u & 0xffff0000u); }

// ---- k1: fused histogram + make_ws (one-shot, conflict-free).
// Blocks [0,NBLK): LDS histogram -> M[k][b].
// Blocks [NBLK,NBLK+8): Ws = W + W^T (coalesced row read + one-time scattered
// transpose read; 64KB total, L2-resident, trivial). ----
__global__ __launch_bounds__(256) void k_hist_ws(
    const int* __restrict__ idx, int E, int nb, unsigned* __restrict__ M,
    const float* __restrict__ W, float* __restrict__ Ws) {
    extern __shared__ unsigned cnt[];
    int bid = blockIdx.x;
    if (bid < NBLK) {
        for (int i = threadIdx.x; i < nb; i += 256) cnt[i] = 0;
        __syncthreads();
        int chunk = (E + NBLK - 1) / NBLK;
        int s = bid * chunk;
        int e_end = min(E, s + chunk);
        for (int e = s + threadIdx.x; e < e_end; e += 256) {
            int i1 = idx[E + e];
            atomicAdd(&cnt[i1 >> 5], 1u);
        }
        __syncthreads();
        for (int i = threadIdx.x; i < nb; i += 256)
            M[(size_t)bid * nb + i] = cnt[i];
    } else {
        int base = (bid - NBLK) * 2048;
        for (int k = threadIdx.x; k < 2048; k += 256) {
            int e = base + k;
            int i = e >> 7, j = e & 127;
            Ws[e] = W[e] + W[j * FDIM + i];
        }
    }
}

// ---- k2: G = F @ Ws (bf16 out), K-chunked LDS staging.
// sWs chunk 16KB + sF 16KB = 32KB -> 5 blocks/CU (20 waves), vs 2 at 80KB. ----
__global__ __launch_bounds__(256, 5) void k_gemm(
    const float* __restrict__ Fm, const float* __restrict__ Ws,
    unsigned short* __restrict__ Gbf, int N) {
    __shared__ float sWs[32 * FDIM];   // 16 KB (one K-chunk)
    __shared__ float sF[32][FDIM];     // 16 KB

    int row0 = blockIdx.x * 32;
    for (int k = threadIdx.x; k < 32 * FDIM / 4; k += 256) {
        int r = k >> 5, c = k & 31;
        int gr = row0 + r;
        float4 v = make_float4(0.f, 0.f, 0.f, 0.f);
        if (gr < N) v = ((const float4*)Fm)[(size_t)gr * (FDIM / 4) + c];
        ((float4*)&sF[r][0])[c] = v;
    }

    int tx = threadIdx.x & 31;
    int ty = threadIdx.x >> 5;
    int c0 = tx * 4;
    float acc[4][4] = {};

    for (int kc = 0; kc < 4; ++kc) {
        __syncthreads();
        for (int k = threadIdx.x; k < 32 * FDIM / 4; k += 256)
            ((float4*)sWs)[k] = ((const float4*)(Ws + kc * 32 * FDIM))[k];
        __syncthreads();
        int i0 = kc * 32;
        for (int i = 0; i < 32; ++i) {
            float4 w = *(const float4*)&sWs[i * FDIM + c0];
            float f0 = sF[ty * 4 + 0][i0 + i];
            float f1 = sF[ty * 4 + 1][i0 + i];
            float f2 = sF[ty * 4 + 2][i0 + i];
            float f3 = sF[ty * 4 + 3][i0 + i];
            acc[0][0] = fmaf(f0, w.x, acc[0][0]); acc[0][1] = fmaf(f0, w.y, acc[0][1]);
            acc[0][2] = fmaf(f0, w.z, acc[0][2]); acc[0][3] = fmaf(f0, w.w, acc[0][3]);
            acc[1][0] = fmaf(f1, w.x, acc[1][0]); acc[1][1] = fmaf(f1, w.y, acc[1][1]);
            acc[1][2] = fmaf(f1, w.z, acc[1][2]); acc[1][3] = fmaf(f1, w.w, acc[1][3]);
            acc[2][0] = fmaf(f2, w.x, acc[2][0]); acc[2][1] = fmaf(f2, w.y, acc[2][1]);
            acc[2][2] = fmaf(f2, w.z, acc[2][2]); acc[2][3] = fmaf(f2, w.w, acc[2][3]);
            acc[3][0] = fmaf(f3, w.x, acc[3][0]); acc[3][1] = fmaf(f3, w.y, acc[3][1]);
            acc[3][2] = fmaf(f3, w.z, acc[3][2]); acc[3][3] = fmaf(f3, w.w, acc[3][3]);
        }
    }

    for (int r = 0; r < 4; ++r) {
        int gr = row0 + ty * 4 + r;
        if (gr < N) {
            ushort4 o;
            o.x = f2bf(acc[r][0]); o.y = f2bf(acc[r][1]);
            o.z = f2bf(acc[r][2]); o.w = f2bf(acc[r][3]);
            *(ushort4*)(Gbf + (size_t)gr * FDIM + c0) = o;
        }
    }
}

// ---- k3: per-bucket totals, tot[b] = sum_k M[k][b] (x8 unrolled, coalesced) ----
__global__ __launch_bounds__(256) void k_btot(const unsigned* __restrict__ M, int nb,
                                              unsigned* __restrict__ tot) {
    int b = blockIdx.x * 256 + threadIdx.x;
    if (b < nb) {
        unsigned s = 0;
        for (int k = 0; k < NBLK; k += 8) {
            unsigned t0 = M[(size_t)(k + 0) * nb + b];
            unsigned t1 = M[(size_t)(k + 1) * nb + b];
            unsigned t2 = M[(size_t)(k + 2) * nb + b];
            unsigned t3 = M[(size_t)(k + 3) * nb + b];
            unsigned t4 = M[(size_t)(k + 4) * nb + b];
            unsigned t5 = M[(size_t)(k + 5) * nb + b];
            unsigned t6 = M[(size_t)(k + 6) * nb + b];
            unsigned t7 = M[(size_t)(k + 7) * nb + b];
            s += t0 + t1 + t2 + t3 + t4 + t5 + t6 + t7;
        }
        tot[b] = s;
    }
}

// ---- k4: single-block exclusive scan of tot -> bucketStart (8/thread) ----
__global__ __launch_bounds__(256) void k_bscan(const unsigned* __restrict__ tot, int nb,
                                               unsigned* __restrict__ bucketStart) {
    __shared__ unsigned wS[4];
    int t = threadIdx.x;
    unsigned v0, v1, v2, v3, v4, v5, v6, v7;
    int b0 = t * 8;
    v0 = (b0 + 0 < nb) ? tot[b0 + 0] : 0u;
    v1 = (b0 + 1 < nb) ? tot[b0 + 1] : 0u;
    v2 = (b0 + 2 < nb) ? tot[b0 + 2] : 0u;
    v3 = (b0 + 3 < nb) ? tot[b0 + 3] : 0u;
    v4 = (b0 + 4 < nb) ? tot[b0 + 4] : 0u;
    v5 = (b0 + 5 < nb) ? tot[b0 + 5] : 0u;
    v6 = (b0 + 6 < nb) ? tot[b0 + 6] : 0u;
    v7 = (b0 + 7 < nb) ? tot[b0 + 7] : 0u;
    unsigned l0 = 0, l1 = v0, l2 = l1 + v1, l3 = l2 + v2, l4 = l3 + v3,
             l5 = l4 + v4, l6 = l5 + v5, l7 = l6 + v6;
    unsigned s = l7 + v7;
    int lane = t & 63, wid = t >> 6;
    unsigned incl = s;
    for (int d = 1; d < 64; d <<= 1) {
        unsigned u = __shfl_up(incl, d, 64);
        if (lane >= d) incl += u;
    }
    if (lane == 63) wS[wid] = incl;
    __syncthreads();
    unsigned wOff = 0;
    for (int i = 0; i < wid; ++i) wOff += wS[i];
    unsigned base = wOff + incl - s;
    if (b0 + 0 < nb) bucketStart[b0 + 0] = base + l0;
    if (b0 + 1 < nb) bucketStart[b0 + 1] = base + l1;
    if (b0 + 2 < nb) bucketStart[b0 + 2] = base + l2;
    if (b0 + 3 < nb) bucketStart[b0 + 3] = base + l3;
    if (b0 + 4 < nb) bucketStart[b0 + 4] = base + l4;
    if (b0 + 5 < nb) bucketStart[b0 + 5] = base + l5;
    if (b0 + 6 < nb) bucketStart[b0 + 6] = base + l6;
    if (b0 + 7 < nb) bucketStart[b0 + 7] = base + l7;
    if (t == 255) bucketStart[nb] = base + s;
}

// ---- k5: per-bucket running prefix over k: M[k][b] -> cursor starts ----
__global__ __launch_bounds__(256) void k_mscan(unsigned* __restrict__ M, int nb,
                                               const unsigned* __restrict__ bucketStart) {
    int b = blockIdx.x * 256 + threadIdx.x;
    if (b < nb) {
        unsigned run = bucketStart[b];
        for (int k = 0; k < NBLK; k += 8) {
            unsigned t0 = M[(size_t)(k + 0) * nb + b];
            unsigned t1 = M[(size_t)(k + 1) * nb + b];
            unsigned t2 = M[(size_t)(k + 2) * nb + b];
            unsigned t3 = M[(size_t)(k + 3) * nb + b];
            unsigned t4 = M[(size_t)(k + 4) * nb + b];
            unsigned t5 = M[(size_t)(k + 5) * nb + b];
            unsigned t6 = M[(size_t)(k + 6) * nb + b];
            unsigned t7 = M[(size_t)(k + 7) * nb + b];
            M[(size_t)(k + 0) * nb + b] = run; run += t0;
            M[(size_t)(k + 1) * nb + b] = run; run += t1;
            M[(size_t)(k + 2) * nb + b] = run; run += t2;
            M[(size_t)(k + 3) * nb + b] = run; run += t3;
            M[(size_t)(k + 4) * nb + b] = run; run += t4;
            M[(size_t)(k + 5) * nb + b] = run; run += t5;
            M[(size_t)(k + 6) * nb + b] = run; run += t6;
            M[(size_t)(k + 7) * nb + b] = run; run += t7;
        }
    }
}

// ---- k6: scatter via LDS cursors. 128 blocks x 512 thr. ----
__global__ __launch_bounds__(512) void k_scatter(const int* __restrict__ idx,
                                                 const int* __restrict__ mol, int E,
                                                 int nb, const unsigned* __restrict__ M,
                                                 unsigned* __restrict__ sortedE) {
    extern __shared__ unsigned cur[];
    int bid = blockIdx.x;
    for (int i = threadIdx.x; i < nb; i += 512)
        cur[i] = M[(size_t)bid * nb + i];
    __syncthreads();
    int chunk = (E + NBLK - 1) / NBLK;
    int s = bid * chunk;
    int e_end = min(E, s + chunk);
    for (int e = s + threadIdx.x; e < e_end; e += 512) {
        int i0 = idx[e];
        int i1 = idx[E + e];
        int m  = mol[e];
        int b  = i1 >> 5;
        int loc = i1 & 31;
        unsigned pos = atomicAdd(&cur[b], 1u);
        sortedE[pos] = (unsigned)i0 | ((unsigned)m << 16) | ((unsigned)loc << 26);
    }
}

// ---- k7: edge kernel (R6 exact, 69us known-good). One WG per bucket. ----
__global__ __launch_bounds__(256) void edge_kernel(
    const unsigned short* __restrict__ Gbf, const float* __restrict__ Fm,
    const unsigned* __restrict__ sortedE, const unsigned* __restrict__ bucketStart,
    float* __restrict__ part, int N, int Mout) {
    __shared__ unsigned short sFrow[BROWS * FDIM];   // 8 KB
    __shared__ float smol[1024];                     // 4 KB

    int b = blockIdx.x;
    int row0 = b * BROWS;
    int nrow = min(BROWS, N - row0);
    for (int k = threadIdx.x; k < nrow * (FDIM / 4); k += 256) {
        int r = k >> 5, c = k & 31;
        float4 v = ((const float4*)(Fm + (size_t)(row0 + r) * FDIM))[c];
        ushort4 o;
        o.x = f2bf(v.x); o.y = f2bf(v.y); o.z = f2bf(v.z); o.w = f2bf(v.w);
        *(ushort4*)(sFrow + r * FDIM + c * 4) = o;
    }
    for (int i = threadIdx.x; i < 1024; i += 256) smol[i] = 0.f;
    __syncthreads();

    const int s = bucketStart[b];
    const int e_end = bucketStart[b + 1];
    const int lane = threadIdx.x & 63;
    const int sub  = lane >> 4;
    const int t16  = lane & 15;
    const int off16 = t16 * 8;
    const int wid  = threadIdx.x >> 6;

    for (int base = s + wid * 4; base < e_end; base += 16) {
        int e = base + sub;
        bool valid = (e < e_end);
        unsigned pk = valid ? sortedE[e] : 0u;
        int i0  = pk & 0xffff;
        int m   = (pk >> 16) & 0x3ff;
        int loc = pk >> 26;
        const uint4 g = *(const uint4*)(Gbf + (size_t)i0 * FDIM + off16);
        const uint4 f = *(const uint4*)(sFrow + loc * FDIM + off16);
        float p;
        p = bf_lo(g.x) * bf_lo(f.x);
        p = fmaf(bf_hi(g.x), bf_hi(f.x), p);
        p = fmaf(bf_lo(g.y), bf_lo(f.y), p);
        p = fmaf(bf_hi(g.y), bf_hi(f.y), p);
        p = fmaf(bf_lo(g.z), bf_lo(f.z), p);
        p = fmaf(bf_hi(g.z), bf_hi(f.z), p);
        p = fmaf(bf_lo(g.w), bf_lo(f.w), p);
        p = fmaf(bf_hi(g.w), bf_hi(f.w), p);
        p += __shfl_xor(p, 1, 16);
        p += __shfl_xor(p, 2, 16);
        p += __shfl_xor(p, 4, 16);
        p += __shfl_xor(p, 8, 16);
        if (t16 == 0 && valid) atomicAdd(&smol[m], p);
    }
    __syncthreads();
    float* prow = part + (size_t)b * 1024;
    for (int i = threadIdx.x; i < 1024; i += 256) prow[i] = smol[i];
}

// ---- k8: reduction, 128 blocks (32 slices x 4 col-chunks), coalesced,
// one atomicAdd per (block,col) into pre-zeroed out. ----
__global__ __launch_bounds__(256) void k_red(const float* __restrict__ part, int nb,
                                             float* __restrict__ out, int Mout) {
    int slice = blockIdx.x >> 2;          // 0..31
    int chunk = blockIdx.x & 3;           // 0..3
    int col = chunk * 256 + threadIdx.x;  // 0..1023
    float s = 0.f;
    for (int b = slice; b < nb; b += 32)
        s += part[(size_t)b * 1024 + col];
    if (col < Mout) atomicAdd(&out[col], s);
}

extern "C" void kernel_launch(void* const* d_in, const int* in_sizes, int n_in,
                              void* d_out, int out_size, void* d_ws, size_t ws_size,
                              hipStream_t stream) {
    const float* Fm = (const float*)d_in[0];
    const float* W  = (const float*)d_in[1];
    const int* idx  = (const int*)d_in[2];
    const int* mol  = (const int*)d_in[3];
    float* out = (float*)d_out;

    const int N = in_sizes[0] / FDIM;   // 50000
    const int E = in_sizes[3];          // 1600000
    const int nb = (N + BROWS - 1) / BROWS;   // 1563
    const int gemmBlocks = (N + 31) / 32;     // 1563

    // workspace layout (~27 MB)
    char* ws = (char*)d_ws;
    size_t o = 0;
    float* Ws = (float*)(ws + o);                    o += 64 * 1024;
    unsigned short* Gbf = (unsigned short*)(ws + o); o += ((size_t)N * FDIM * 2 + 255) & ~(size_t)255;
    unsigned* sortedE = (unsigned*)(ws + o);         o += ((size_t)E * 4 + 255) & ~(size_t)255;
    unsigned* M = (unsigned*)(ws + o);               o += ((size_t)NBLK * nb * 4 + 255) & ~(size_t)255;
    unsigned* tot = (unsigned*)(ws + o);             o += ((size_t)nb * 4 + 255) & ~(size_t)255;
    unsigned* bucketStart = (unsigned*)(ws + o);     o += ((size_t)(nb + 1) * 4 + 255) & ~(size_t)255;
    float* part = (float*)(ws + o);                  o += (size_t)nb * 1024 * sizeof(float);

    hipMemsetAsync(out, 0, (size_t)out_size * sizeof(float), stream);

    k_hist_ws<<<NBLK + 8, 256, (size_t)nb * 4, stream>>>(idx, E, nb, M, W, Ws);
    k_gemm<<<gemmBlocks, 256, 0, stream>>>(Fm, Ws, Gbf, N);
    k_btot<<<(nb + 255) / 256, 256, 0, stream>>>(M, nb, tot);
    k_bscan<<<1, 256, 0, stream>>>(tot, nb, bucketStart);
    k_mscan<<<(nb + 255) / 256, 256, 0, stream>>>(M, nb, bucketStart);
    k_scatter<<<NBLK, 512, (size_t)nb * 4, stream>>>(idx, mol, E, nb, M, sortedE);
    edge_kernel<<<nb, 256, 0, stream>>>(Gbf, Fm, sortedE, bucketStart, part, N, out_size);
    k_red<<<128, 256, 0, stream>>>(part, nb, out, out_size);
}